// Round 9
// baseline (1669.462 us; speedup 1.0000x reference)
//
#include <hip/hip_runtime.h>
#include <cmath>

#define NN 128
#define TT 20
#define ERNN 256
#define TEMPSC 15.875f /* (N-1)/sqrt(ATT) = 127/8 */

typedef __attribute__((ext_vector_type(8))) short bf16x8;
typedef __attribute__((ext_vector_type(4))) float f32x4;

__device__ __forceinline__ float sigm(float x){ return 1.f/(1.f+__expf(-x)); }
__device__ __forceinline__ float b2f(unsigned short u){ union{unsigned int i; float f;} v; v.i = ((unsigned int)u)<<16; return v.f; }
__device__ __forceinline__ unsigned short f2b(float x){ union{float f; unsigned int u;} v; v.f = x; unsigned int r = v.u + 0x7fffu + ((v.u>>16)&1u); return (unsigned short)(r>>16); }

typedef __attribute__((address_space(3))) unsigned int lds_u32;
typedef __attribute__((address_space(1))) unsigned int glb_u32;
__device__ __forceinline__ void glds16(const void* g, void* l){
    __builtin_amdgcn_global_load_lds((const glb_u32*)g, (lds_u32*)l, 16, 0, 0);
}

// chunked h: [tile=r>>7][kc=d>>3 (32)][row=r&127][q=d&7]
__device__ __forceinline__ size_t hoff(int r, int d){
    return ((size_t)((r>>7)*32 + (d>>3))*128 + (r&127))*8 + (d&7);
}

__global__ void k_transpose(const float* __restrict__ s, float* __restrict__ d, int R, int C){
    int i = blockIdx.x*256 + threadIdx.x;
    if (i < R*C){ int r = i / C, c = i - r*C; d[c*R + r] = s[i]; }
}

__global__ void k_bias_sum(const float* __restrict__ a, const float* __restrict__ b,
                           float* __restrict__ o, int n){
    int i = blockIdx.x*256 + threadIdx.x;
    if (i < n) o[i] = a[i] + b[i];
}

// W chunked: [nt(8)][kchunk(40)][col(128)][8], col gate-interleaved (ch=(c>>6)*16+(c&15), g=(c>>4)&3)
__global__ void k_prep_w(const float* __restrict__ wih, const float* __restrict__ whh,
                         unsigned short* __restrict__ wHi, unsigned short* __restrict__ wLo){
    int idx = blockIdx.x*256 + threadIdx.x;
    if (idx >= 1024*320) return;
    int c = idx / 320, k = idx - c*320;
    int ch = ((c>>6)<<4) + (c&15), g = (c>>4)&3;
    int r = g*256 + ch;
    float v = (k < 64) ? wih[r*64 + k] : whh[r*256 + (k-64)];
    unsigned short hi = f2b(v);
    size_t dst = ((size_t)((c>>7)*40 + (k>>3))*128 + (c&127))*8 + (k&7);
    wHi[dst] = hi;
    wLo[dst] = f2b(v - b2f(hi));
}

__global__ void k_prep_b(const float* __restrict__ bih, const float* __restrict__ bhh,
                         float* __restrict__ bs){
    int c = blockIdx.x*256 + threadIdx.x;
    if (c < 1024){ int ch = ((c>>6)<<4)+(c&15), g=(c>>4)&3; int r = g*256+ch; bs[c] = bih[r] + bhh[r]; }
}

// encoder for ALL steps, chunked: [t][tile(128)][kc(8)][row(128)][8]
__global__ void k_prep_xenc(const float* __restrict__ edges,
                            const float* __restrict__ s_enc_w, const float* __restrict__ s_enc_b,
                            const float* __restrict__ t_enc_w, const float* __restrict__ t_enc_b,
                            unsigned short* __restrict__ xe){
    size_t idx = (size_t)blockIdx.x*256 + threadIdx.x;
    if (idx >= (size_t)TT*16384*64) return;
    int t = (int)(idx / (16384*64));
    int rem = (int)(idx - (size_t)t*16384*64);
    int r = rem >> 6, m = rem & 63;
    bool sp = (r < 16256);
    int row_ij;
    if (sp) { int i = r/127, jj = r - i*127; row_ij = i*NN + jj + (jj>=i ? 1:0); }
    else    { row_ij = (r - 16256)*(NN+1); }
    const float* w = sp ? s_enc_w : t_enc_w;
    const float* b = sp ? s_enc_b : t_enc_b;
    float e0 = edges[((size_t)t*16384 + row_ij)*2];
    float e1 = edges[((size_t)t*16384 + row_ij)*2 + 1];
    float v = fmaxf(fmaf(w[m*2], e0, fmaf(w[m*2+1], e1, b[m])), 0.f);
    xe[(((size_t)t*128 + (r>>7))*8 + (m>>3))*1024 + (size_t)(r&127)*8 + (m&7)] = f2b(v);
}

// gather (i,j)-layout initial state into se-order; h chunked bf16, c linear fp32
__global__ void k_init_state(const float* __restrict__ h0, const float* __restrict__ c0,
                             unsigned short* __restrict__ hHi, float* __restrict__ c_all){
    int idx = blockIdx.x*256 + threadIdx.x;
    if (idx >= 16384*256) return;
    int r = idx >> 8, d = idx & 255;
    int row_ij;
    if (r < 16256){ int i = r/127, jj = r - i*127; row_ij = i*NN + jj + (jj>=i ? 1:0); }
    else          { row_ij = (r - 16256)*(NN+1); }
    hHi[hoff(r, d)] = f2b(h0[row_ij*ERNN + d]);
    c_all[idx] = c0[row_ij*ERNN + d];
}

// Edge LSTM: staged GEMM, X = [xenc(64) | h(256)], K=320, BK=32, 10 K-steps.
// 2-product (A bf16, W split hi+lo). Double-buffered LDS, ONE barrier per K-step:
// __syncthreads' implicit vmcnt(0) drains exactly the current buffer's glds
// (issued last iteration -> latency hidden under previous compute). stage(next)
// is issued right after the barrier, targeting the buffer all waves just
// finished reading (safe: they crossed the barrier after compute).
__global__ __launch_bounds__(256) void k_edge(
    const unsigned short* __restrict__ xenc_t,   // this step's chunked enc
    const unsigned short* __restrict__ h_in, unsigned short* __restrict__ h_out,
    float* __restrict__ hf_out, float* __restrict__ c_all,
    const unsigned short* __restrict__ s_wHi, const unsigned short* __restrict__ s_wLo,
    const float* __restrict__ s_bs,
    const unsigned short* __restrict__ t_wHi, const unsigned short* __restrict__ t_wLo,
    const float* __restrict__ t_bs)
{
    __shared__ unsigned short Ah[2][128*32];   // 16KB
    __shared__ unsigned short Bh[2][128*32];   // 16KB
    __shared__ unsigned short Bl[2][128*32];   // 16KB
    const int tid = threadIdx.x, lane = tid & 63, wid = tid >> 6;
    // XCD-chunked swizzle (bijective on 1024): all 8 nt of a bm + 16 bm per XCD
    const int wg = (blockIdx.x & 7)*128 + (blockIdx.x >> 3);
    const int bm = wg >> 3, nt = wg & 7;
    const bool sp = (bm < 127);
    const int rbase = bm * 128;
    const unsigned short* wHi = sp ? s_wHi : t_wHi;
    const unsigned short* wLo = sp ? s_wLo : t_wLo;
    const float* bs = sp ? s_bs : t_bs;
    const int wr = wid >> 1, wc = wid & 1;

    // staging: K-step ks covers k-chunks ks*4..ks*4+3 (4096 shorts per tile)
    auto stage = [&](int ks, int b){
        #pragma unroll
        for (int i2 = 0; i2 < 2; ++i2) {
            int L = wid*2 + i2;            // 0..7 half-chunks of 512 shorts
            int so = L*512 + lane*8;
            const unsigned short* asrc = (ks < 2)
                ? xenc_t + ((size_t)bm*8 + ks*4)*1024 + so
                : h_in   + ((size_t)bm*32 + (ks-2)*4)*1024 + so;
            glds16(asrc, (char*)&Ah[b][0] + L*1024);
            size_t wb = ((size_t)nt*40 + ks*4)*1024 + so;
            glds16(wHi + wb, (char*)&Bh[b][0] + L*1024);
            glds16(wLo + wb, (char*)&Bl[b][0] + L*1024);
        }
    };
    stage(0, 0);

    f32x4 acc[4][4];
    #pragma unroll
    for (int m = 0; m < 4; ++m)
        #pragma unroll
        for (int g = 0; g < 4; ++g)
            acc[m][g] = (f32x4){0.f,0.f,0.f,0.f};

    const int arow = wr*64 + (lane & 15);
    const int bcol = wc*64 + (lane & 15);
    const int kg = lane >> 4;      // 0..3 -> local k-chunk
    #pragma unroll
    for (int ks = 0; ks < 10; ++ks) {
        const int cur = ks & 1;
        __syncthreads();           // implicit vmcnt(0): cur buffer landed; all waves past prev compute
        if (ks < 9) stage(ks+1, cur^1);   // flies during this step's ds_read+MFMA
        bf16x8 a[4], bh[4];
        #pragma unroll
        for (int m = 0; m < 4; ++m) a[m] = *(const bf16x8*)&Ah[cur][(kg*128 + arow + m*16)*8];
        #pragma unroll
        for (int g = 0; g < 4; ++g) bh[g] = *(const bf16x8*)&Bh[cur][(kg*128 + bcol + g*16)*8];
        #pragma unroll
        for (int m = 0; m < 4; ++m)
            #pragma unroll
            for (int g = 0; g < 4; ++g)
                acc[m][g] = __builtin_amdgcn_mfma_f32_16x16x32_bf16(a[m], bh[g], acc[m][g], 0, 0, 0);
        bf16x8 bl[4];
        #pragma unroll
        for (int g = 0; g < 4; ++g) bl[g] = *(const bf16x8*)&Bl[cur][(kg*128 + bcol + g*16)*8];
        #pragma unroll
        for (int m = 0; m < 4; ++m)
            #pragma unroll
            for (int g = 0; g < 4; ++g)
                acc[m][g] = __builtin_amdgcn_mfma_f32_16x16x32_bf16(a[m], bl[g], acc[m][g], 0, 0, 0);
    }

    // epilogue: lane-local gates (n-fragment index == gate)
    const int chl = lane & 15, q4 = (lane >> 4)*4;
    const int ch = (nt*2 + wc)*16 + chl;           // channel in [0,256)
    const int cbase = nt*128 + wc*64 + chl;        // permuted col of gate i
    const float b0 = bs[cbase], b1 = bs[cbase+16], b2 = bs[cbase+32], b3 = bs[cbase+48];
    #pragma unroll
    for (int m = 0; m < 4; ++m) {
        #pragma unroll
        for (int rg = 0; rg < 4; ++rg) {
            int lrow = wr*64 + m*16 + q4 + rg;
            int row = rbase + lrow;
            float gi = acc[m][0][rg] + b0;
            float gf = acc[m][1][rg] + b1;
            float gg = acc[m][2][rg] + b2;
            float go = acc[m][3][rg] + b3;
            size_t off = (size_t)row*256 + ch;
            float c_old = c_all[off];
            float c2 = sigm(gf)*c_old + sigm(gi)*tanhf(gg);
            float h2 = sigm(go)*tanhf(c2);
            c_all[off] = c2;
            h_out[((size_t)(bm*32 + (ch>>3))*128 + lrow)*8 + (ch&7)] = f2b(h2);
            hf_out[off] = h2;   // linear fp32 for the node kernel
        }
    }
}

// Per-node: attention (folded) + node LSTM + output. Reads linear fp32 hf.
__global__ __launch_bounds__(256) void k_node(
    const float* __restrict__ nodes_t,
    const float* __restrict__ h,                 // [16384,256] fp32, se-order
    float* __restrict__ h_n, float* __restrict__ c_n,
    float* __restrict__ out_t,
    const float* __restrict__ att_t_w, const float* __restrict__ att_t_b,
    const float* __restrict__ att_s_w, const float* __restrict__ att_s_b,
    const float* __restrict__ n_enc_w, const float* __restrict__ n_enc_b,
    const float* __restrict__ n_attn_w, const float* __restrict__ n_attn_b,
    const float* __restrict__ n_wT, const float* __restrict__ n_bsum,
    const float* __restrict__ out_w, const float* __restrict__ out_b)
{
    const int i = blockIdx.x, tid = threadIdx.x;
    __shared__ float ht[ERNN];
    __shared__ float te[64];
    __shared__ float u[ERNN];
    __shared__ float lg[128];
    __shared__ float cat[512];
    __shared__ float xc[128];
    __shared__ float hnl[128];
    __shared__ float gl[512];
    __shared__ float smax, ssum, c0s;

    ht[tid] = h[(size_t)(16256 + i)*256 + tid];
    __syncthreads();
    if (tid < 64) {
        float s = att_t_b[tid];
        const float* wr = att_t_w + tid*ERNN;
        for (int k = 0; k < ERNN; ++k) s = fmaf(wr[k], ht[k], s);
        te[tid] = s;
    }
    __syncthreads();
    {
        float s = 0.f;
        for (int m = 0; m < 64; ++m) s = fmaf(att_s_w[m*ERNN + tid], te[m], s);
        u[tid] = s;
    }
    if (tid == 0) {
        float s = 0.f;
        for (int m = 0; m < 64; ++m) s = fmaf(te[m], att_s_b[m], s);
        c0s = s;
    }
    __syncthreads();
    {
        int slot = tid >> 1, half = tid & 1;
        float part = 0.f;
        if (slot < 127) {
            const float4* hs = (const float4*)(h + (size_t)(i*127 + slot)*256 + half*128);
            const float4* uu = (const float4*)(u + half*128);
            #pragma unroll 8
            for (int d = 0; d < 32; ++d) {
                float4 a = hs[d], b = uu[d];
                part = fmaf(a.x, b.x, part); part = fmaf(a.y, b.y, part);
                part = fmaf(a.z, b.z, part); part = fmaf(a.w, b.w, part);
            }
        }
        part += __shfl_xor(part, 1);
        if (slot < 127 && (half == 0)) lg[slot] = (part + c0s) * TEMPSC;
        if (tid == 255) lg[127] = -1e30f;
    }
    __syncthreads();
    if (tid < 64) {
        float a = fmaxf(lg[tid], lg[tid+64]);
        for (int off = 32; off; off >>= 1) a = fmaxf(a, __shfl_xor(a, off));
        if (tid == 0) smax = a;
    }
    __syncthreads();
    if (tid < 128) lg[tid] = (tid < 127) ? __expf(lg[tid] - smax) : 0.f;
    __syncthreads();
    if (tid < 64) {
        float a = lg[tid] + lg[tid+64];
        for (int off = 32; off; off >>= 1) a += __shfl_xor(a, off);
        if (tid == 0) ssum = a;
    }
    __syncthreads();
    {
        float acc = 0.f;
        for (int slot = 0; slot < 127; ++slot)
            acc = fmaf(lg[slot], h[(size_t)(i*127 + slot)*256 + tid], acc);
        cat[tid] = ht[tid];
        cat[256 + tid] = acc / ssum;
    }
    if (tid < 128) hnl[tid] = h_n[i*128 + tid];
    __syncthreads();
    if (tid < 64) {
        float p0 = nodes_t[i*2], p1 = nodes_t[i*2+1];
        xc[tid] = fmaxf(fmaf(n_enc_w[tid*2], p0, fmaf(n_enc_w[tid*2+1], p1, n_enc_b[tid])), 0.f);
    } else if (tid < 128) {
        int m = tid - 64;
        float s = n_attn_b[m];
        const float* wr = n_attn_w + m*512;
        for (int d = 0; d < 512; ++d) s = fmaf(wr[d], cat[d], s);
        xc[tid] = fmaxf(s, 0.f);
    }
    __syncthreads();
    #pragma unroll
    for (int rep = 0; rep < 2; ++rep) {
        int n = tid + rep*256;
        float s = n_bsum[n];
        for (int k = 0; k < 128; ++k) s = fmaf(n_wT[k*512 + n], xc[k], s);
        for (int k = 0; k < 128; ++k) s = fmaf(n_wT[(128+k)*512 + n], hnl[k], s);
        gl[n] = s;
    }
    __syncthreads();
    if (tid < 128) {
        float co = c_n[i*128 + tid];
        float c2 = sigm(gl[128+tid])*co + sigm(gl[tid])*tanhf(gl[256+tid]);
        float h2 = sigm(gl[384+tid])*tanhf(c2);
        c_n[i*128+tid] = c2;
        h_n[i*128+tid] = h2;
        hnl[tid] = h2;
    }
    __syncthreads();
    if (tid < 5) {
        float s = out_b[tid];
        const float* wr = out_w + tid*128;
        for (int k = 0; k < 128; ++k) s = fmaf(wr[k], hnl[k], s);
        out_t[i*5 + tid] = s;
    }
}

extern "C" void kernel_launch(void* const* d_in, const int* in_sizes, int n_in,
                              void* d_out, int out_size, void* d_ws, size_t ws_size,
                              hipStream_t stream)
{
    const float* nodes   = (const float*)d_in[0];
    const float* edges   = (const float*)d_in[1];
    const float* h_e0    = (const float*)d_in[2];
    const float* c_e0    = (const float*)d_in[3];
    const float* h_n0    = (const float*)d_in[4];
    const float* c_n0    = (const float*)d_in[5];
    const float* t_enc_w = (const float*)d_in[6];
    const float* t_enc_b = (const float*)d_in[7];
    const float* t_wih   = (const float*)d_in[8];
    const float* t_whh   = (const float*)d_in[9];
    const float* t_bih   = (const float*)d_in[10];
    const float* t_bhh   = (const float*)d_in[11];
    const float* s_enc_w = (const float*)d_in[12];
    const float* s_enc_b = (const float*)d_in[13];
    const float* s_wih   = (const float*)d_in[14];
    const float* s_whh   = (const float*)d_in[15];
    const float* s_bih   = (const float*)d_in[16];
    const float* s_bhh   = (const float*)d_in[17];
    const float* att_t_w = (const float*)d_in[18];
    const float* att_t_b = (const float*)d_in[19];
    const float* att_s_w = (const float*)d_in[20];
    const float* att_s_b = (const float*)d_in[21];
    const float* n_enc_w = (const float*)d_in[22];
    const float* n_enc_b = (const float*)d_in[23];
    const float* n_attn_w= (const float*)d_in[24];
    const float* n_attn_b= (const float*)d_in[25];
    const float* n_wih   = (const float*)d_in[26];
    const float* n_whh   = (const float*)d_in[27];
    const float* n_bih   = (const float*)d_in[28];
    const float* n_bhh   = (const float*)d_in[29];
    const float* out_w   = (const float*)d_in[30];
    const float* out_b   = (const float*)d_in[31];
    float* out = (float*)d_out;

    char* p = (char*)d_ws;
    float* c_all = (float*)p;            p += (size_t)16384*256*4;
    float* hf    = (float*)p;            p += (size_t)16384*256*4;
    float* h_nn  = (float*)p;            p += 128*128*4;
    float* c_nn  = (float*)p;            p += 128*128*4;
    float* s_bs  = (float*)p;            p += 1024*4;
    float* t_bs  = (float*)p;            p += 1024*4;
    float* n_wT  = (float*)p;            p += 256*512*4;
    float* n_bs  = (float*)p;            p += 512*4;
    unsigned short* h_a  = (unsigned short*)p;  p += (size_t)16384*256*2;
    unsigned short* h_b  = (unsigned short*)p;  p += (size_t)16384*256*2;
    unsigned short* xenc = (unsigned short*)p;  p += (size_t)TT*16384*64*2;
    unsigned short* s_wHi = (unsigned short*)p; p += 1024*320*2;
    unsigned short* s_wLo = (unsigned short*)p; p += 1024*320*2;
    unsigned short* t_wHi = (unsigned short*)p; p += 1024*320*2;
    unsigned short* t_wLo = (unsigned short*)p; p += 1024*320*2;

    hipMemcpyAsync(h_nn, h_n0, 128*128*sizeof(float), hipMemcpyDeviceToDevice, stream);
    hipMemcpyAsync(c_nn, c_n0, 128*128*sizeof(float), hipMemcpyDeviceToDevice, stream);

    k_init_state<<<16384, 256, 0, stream>>>(h_e0, c_e0, h_a, c_all);
    k_prep_w<<<1280, 256, 0, stream>>>(s_wih, s_whh, s_wHi, s_wLo);
    k_prep_w<<<1280, 256, 0, stream>>>(t_wih, t_whh, t_wHi, t_wLo);
    k_prep_b<<<4, 256, 0, stream>>>(s_bih, s_bhh, s_bs);
    k_prep_b<<<4, 256, 0, stream>>>(t_bih, t_bhh, t_bs);
    k_prep_xenc<<<81920, 256, 0, stream>>>(edges, s_enc_w, s_enc_b, t_enc_w, t_enc_b, xenc);
    k_transpose<<<(512*128+255)/256, 256, 0, stream>>>(n_wih, n_wT, 512, 128);
    k_transpose<<<(512*128+255)/256, 256, 0, stream>>>(n_whh, n_wT + 128*512, 512, 128);
    k_bias_sum<<<2, 256, 0, stream>>>(n_bih, n_bhh, n_bs, 512);

    for (int t = 0; t < TT; ++t) {
        const unsigned short* h_in = (t & 1) ? h_b : h_a;
        unsigned short*       h_out= (t & 1) ? h_a : h_b;
        k_edge<<<1024, 256, 0, stream>>>(xenc + (size_t)t*16384*64,
            h_in, h_out, hf, c_all,
            s_wHi, s_wLo, s_bs, t_wHi, t_wLo, t_bs);
        k_node<<<NN, 256, 0, stream>>>(nodes + (size_t)t*NN*2, hf, h_nn, c_nn,
            out + (size_t)t*NN*5,
            att_t_w, att_t_b, att_s_w, att_s_b, n_enc_w, n_enc_b,
            n_attn_w, n_attn_b, n_wT, n_bs, out_w, out_b);
    }
}

// Round 10
// 1457.334 us; speedup vs baseline: 1.1456x; 1.1456x over previous
//
#include <hip/hip_runtime.h>
#include <cmath>

#define NN 128
#define TT 20
#define ERNN 256
#define TEMPSC 15.875f /* (N-1)/sqrt(ATT) = 127/8 */

typedef __attribute__((ext_vector_type(8))) short bf16x8;
typedef __attribute__((ext_vector_type(4))) float f32x4;

__device__ __forceinline__ float sigm(float x){ return 1.f/(1.f+__expf(-x)); }
__device__ __forceinline__ float b2f(unsigned short u){ union{unsigned int i; float f;} v; v.i = ((unsigned int)u)<<16; return v.f; }
__device__ __forceinline__ unsigned short f2b(float x){ union{float f; unsigned int u;} v; v.f = x; unsigned int r = v.u + 0x7fffu + ((v.u>>16)&1u); return (unsigned short)(r>>16); }

typedef __attribute__((address_space(3))) unsigned int lds_u32;
typedef __attribute__((address_space(1))) unsigned int glb_u32;
__device__ __forceinline__ void glds16(const void* g, void* l){
    __builtin_amdgcn_global_load_lds((const glb_u32*)g, (lds_u32*)l, 16, 0, 0);
}

// chunked h: [tile=r>>7][kc=d>>3 (32)][row=r&127][q=d&7]
__device__ __forceinline__ size_t hoff(int r, int d){
    return ((size_t)((r>>7)*32 + (d>>3))*128 + (r&127))*8 + (d&7);
}

__global__ void k_transpose(const float* __restrict__ s, float* __restrict__ d, int R, int C){
    int i = blockIdx.x*256 + threadIdx.x;
    if (i < R*C){ int r = i / C, c = i - r*C; d[c*R + r] = s[i]; }
}

__global__ void k_bias_sum(const float* __restrict__ a, const float* __restrict__ b,
                           float* __restrict__ o, int n){
    int i = blockIdx.x*256 + threadIdx.x;
    if (i < n) o[i] = a[i] + b[i];
}

// W chunked: [nt(8)][kchunk(40)][col(128)][8], col gate-interleaved (ch=(c>>6)*16+(c&15), g=(c>>4)&3)
__global__ void k_prep_w(const float* __restrict__ wih, const float* __restrict__ whh,
                         unsigned short* __restrict__ wHi, unsigned short* __restrict__ wLo){
    int idx = blockIdx.x*256 + threadIdx.x;
    if (idx >= 1024*320) return;
    int c = idx / 320, k = idx - c*320;
    int ch = ((c>>6)<<4) + (c&15), g = (c>>4)&3;
    int r = g*256 + ch;
    float v = (k < 64) ? wih[r*64 + k] : whh[r*256 + (k-64)];
    unsigned short hi = f2b(v);
    size_t dst = ((size_t)((c>>7)*40 + (k>>3))*128 + (c&127))*8 + (k&7);
    wHi[dst] = hi;
    wLo[dst] = f2b(v - b2f(hi));
}

__global__ void k_prep_b(const float* __restrict__ bih, const float* __restrict__ bhh,
                         float* __restrict__ bs){
    int c = blockIdx.x*256 + threadIdx.x;
    if (c < 1024){ int ch = ((c>>6)<<4)+(c&15), g=(c>>4)&3; int r = g*256+ch; bs[c] = bih[r] + bhh[r]; }
}

// encoder for ALL steps, chunked: [t][tile(128)][kc(8)][row(128)][8]
__global__ void k_prep_xenc(const float* __restrict__ edges,
                            const float* __restrict__ s_enc_w, const float* __restrict__ s_enc_b,
                            const float* __restrict__ t_enc_w, const float* __restrict__ t_enc_b,
                            unsigned short* __restrict__ xe){
    size_t idx = (size_t)blockIdx.x*256 + threadIdx.x;
    if (idx >= (size_t)TT*16384*64) return;
    int t = (int)(idx / (16384*64));
    int rem = (int)(idx - (size_t)t*16384*64);
    int r = rem >> 6, m = rem & 63;
    bool sp = (r < 16256);
    int row_ij;
    if (sp) { int i = r/127, jj = r - i*127; row_ij = i*NN + jj + (jj>=i ? 1:0); }
    else    { row_ij = (r - 16256)*(NN+1); }
    const float* w = sp ? s_enc_w : t_enc_w;
    const float* b = sp ? s_enc_b : t_enc_b;
    float e0 = edges[((size_t)t*16384 + row_ij)*2];
    float e1 = edges[((size_t)t*16384 + row_ij)*2 + 1];
    float v = fmaxf(fmaf(w[m*2], e0, fmaf(w[m*2+1], e1, b[m])), 0.f);
    xe[(((size_t)t*128 + (r>>7))*8 + (m>>3))*1024 + (size_t)(r&127)*8 + (m&7)] = f2b(v);
}

// gather (i,j)-layout initial state into se-order; h chunked bf16, c linear fp32
__global__ void k_init_state(const float* __restrict__ h0, const float* __restrict__ c0,
                             unsigned short* __restrict__ hHi, float* __restrict__ c_all){
    int idx = blockIdx.x*256 + threadIdx.x;
    if (idx >= 16384*256) return;
    int r = idx >> 8, d = idx & 255;
    int row_ij;
    if (r < 16256){ int i = r/127, jj = r - i*127; row_ij = i*NN + jj + (jj>=i ? 1:0); }
    else          { row_ij = (r - 16256)*(NN+1); }
    hHi[hoff(r, d)] = f2b(h0[row_ij*ERNN + d]);
    c_all[idx] = c0[row_ij*ERNN + d];
}

// Edge LSTM: staged GEMM, X = [xenc(64) | h(256)], K=320, BK=32, 10 K-steps.
// Tiling: BM=128 x BN=64 perm-cols, wave = 32 rows x 64 cols -> acc[2][4] (32 VGPR).
// LDS 16KB, grid 2048 = 8 blocks/CU exactly resident (full occupancy).
// 2-product (A bf16, W split hi+lo); all staging sources pre-chunked (1KB/glds).
__global__ __launch_bounds__(256) void k_edge(
    const unsigned short* __restrict__ xenc_t,   // this step's chunked enc
    const unsigned short* __restrict__ h_in, unsigned short* __restrict__ h_out,
    unsigned short* __restrict__ hl_out, float* __restrict__ c_all,
    const unsigned short* __restrict__ s_wHi, const unsigned short* __restrict__ s_wLo,
    const float* __restrict__ s_bs,
    const unsigned short* __restrict__ t_wHi, const unsigned short* __restrict__ t_wLo,
    const float* __restrict__ t_bs)
{
    __shared__ unsigned short Ah[128*32];   // 8KB  [kc(4)][row(128)][8]
    __shared__ unsigned short Bh[64*32];    // 4KB  [kc(4)][col(64)][8]
    __shared__ unsigned short Bl[64*32];    // 4KB
    const int tid = threadIdx.x, lane = tid & 63, wid = tid >> 6;
    // XCD-chunked swizzle (bijective on 2048): 256 wg per XCD = 16 bm x all 16 nt
    const int wg = (blockIdx.x & 7)*256 + (blockIdx.x >> 3);
    const int bm = wg >> 4, nt = wg & 15;     // nt in [0,16): 64 perm-cols each
    const bool sp = (bm < 127);
    const int rbase = bm * 128;
    const unsigned short* wHi = sp ? s_wHi : t_wHi;
    const unsigned short* wLo = sp ? s_wLo : t_wLo;
    const float* bs = sp ? s_bs : t_bs;
    const int nt128 = nt >> 1, colh = (nt & 1)*64;

    // staging: wave wid handles k-chunk kc=wid of this K-step (4 chunks/step)
    auto stage = [&](int ks){
        // A: 128 rows x 8 shorts = 1024 shorts = 2 glds
        const unsigned short* asrc = (ks < 2)
            ? xenc_t + ((size_t)bm*8  + ks*4     + wid)*1024
            : h_in   + ((size_t)bm*32 + (ks-2)*4 + wid)*1024;
        glds16(asrc + lane*8,       (char*)Ah + wid*2048);
        glds16(asrc + 512 + lane*8, (char*)Ah + wid*2048 + 1024);
        // B: 64 cols x 8 shorts = 512 shorts = 1 glds each
        size_t wb = ((size_t)(nt128*40 + ks*4 + wid)*128 + colh)*8 + lane*8;
        glds16(wHi + wb, (char*)Bh + wid*1024);
        glds16(wLo + wb, (char*)Bl + wid*1024);
    };
    stage(0);

    f32x4 acc[2][4];
    #pragma unroll
    for (int m = 0; m < 2; ++m)
        #pragma unroll
        for (int g = 0; g < 4; ++g)
            acc[m][g] = (f32x4){0.f,0.f,0.f,0.f};

    const int arow = wid*32 + (lane & 15);    // wave covers rows wid*32..+31
    const int bcol = lane & 15;
    const int kg = lane >> 4;                 // 0..3 -> local k-chunk
    for (int ks = 0; ; ++ks) {
        __syncthreads();   // drains vmcnt (glds landed)
        bf16x8 a[2], bb[4];
        #pragma unroll
        for (int m = 0; m < 2; ++m) a[m] = *(const bf16x8*)&Ah[(kg*128 + arow + m*16)*8];
        #pragma unroll
        for (int g = 0; g < 4; ++g) bb[g] = *(const bf16x8*)&Bh[(kg*64 + bcol + g*16)*8];
        #pragma unroll
        for (int m = 0; m < 2; ++m)
            #pragma unroll
            for (int g = 0; g < 4; ++g)
                acc[m][g] = __builtin_amdgcn_mfma_f32_16x16x32_bf16(a[m], bb[g], acc[m][g], 0, 0, 0);
        #pragma unroll
        for (int g = 0; g < 4; ++g) bb[g] = *(const bf16x8*)&Bl[(kg*64 + bcol + g*16)*8];
        #pragma unroll
        for (int m = 0; m < 2; ++m)
            #pragma unroll
            for (int g = 0; g < 4; ++g)
                acc[m][g] = __builtin_amdgcn_mfma_f32_16x16x32_bf16(a[m], bb[g], acc[m][g], 0, 0, 0);
        if (ks == 9) break;
        __syncthreads();
        stage(ks+1);
    }

    // epilogue: lane-local gates (g-fragment index == gate)
    const int chl = lane & 15, q4 = (lane >> 4)*4;
    const int ch = nt*16 + chl;               // channel in [0,256)
    const int cbase = nt*64 + chl;            // permuted col of gate i
    const float b0 = bs[cbase], b1 = bs[cbase+16], b2 = bs[cbase+32], b3 = bs[cbase+48];
    #pragma unroll
    for (int m = 0; m < 2; ++m) {
        #pragma unroll
        for (int rg = 0; rg < 4; ++rg) {
            int lrow = wid*32 + m*16 + q4 + rg;
            int row = rbase + lrow;
            float gi = acc[m][0][rg] + b0;
            float gf = acc[m][1][rg] + b1;
            float gg = acc[m][2][rg] + b2;
            float go = acc[m][3][rg] + b3;
            size_t off = (size_t)row*256 + ch;
            float c_old = c_all[off];
            float c2 = sigm(gf)*c_old + sigm(gi)*tanhf(gg);
            float h2 = sigm(go)*tanhf(c2);
            c_all[off] = c2;
            unsigned short hb = f2b(h2);
            h_out[((size_t)(bm*32 + (ch>>3))*128 + lrow)*8 + (ch&7)] = hb;  // chunked (GEMM)
            hl_out[off] = hb;                                              // linear (node)
        }
    }
}

// Per-node: attention (folded) + node LSTM + output. Reads linear bf16 h.
__global__ __launch_bounds__(256) void k_node(
    const float* __restrict__ nodes_t,
    const unsigned short* __restrict__ hl,       // [16384,256] bf16, se-order
    float* __restrict__ h_n, float* __restrict__ c_n,
    float* __restrict__ out_t,
    const float* __restrict__ att_t_w, const float* __restrict__ att_t_b,
    const float* __restrict__ att_s_w, const float* __restrict__ att_s_b,
    const float* __restrict__ n_enc_w, const float* __restrict__ n_enc_b,
    const float* __restrict__ n_attn_w, const float* __restrict__ n_attn_b,
    const float* __restrict__ n_wT, const float* __restrict__ n_bsum,
    const float* __restrict__ out_w, const float* __restrict__ out_b)
{
    const int i = blockIdx.x, tid = threadIdx.x;
    __shared__ float ht[ERNN];
    __shared__ float te[64];
    __shared__ float u[ERNN];
    __shared__ float lg[128];
    __shared__ float cat[512];
    __shared__ float xc[128];
    __shared__ float hnl[128];
    __shared__ float gl[512];
    __shared__ float smax, ssum, c0s;

    ht[tid] = b2f(hl[(size_t)(16256 + i)*256 + tid]);
    __syncthreads();
    if (tid < 64) {
        float s = att_t_b[tid];
        const float* wr = att_t_w + tid*ERNN;
        for (int k = 0; k < ERNN; ++k) s = fmaf(wr[k], ht[k], s);
        te[tid] = s;
    }
    __syncthreads();
    {
        float s = 0.f;
        for (int m = 0; m < 64; ++m) s = fmaf(att_s_w[m*ERNN + tid], te[m], s);
        u[tid] = s;
    }
    if (tid == 0) {
        float s = 0.f;
        for (int m = 0; m < 64; ++m) s = fmaf(te[m], att_s_b[m], s);
        c0s = s;
    }
    __syncthreads();
    {
        int slot = tid >> 1, half = tid & 1;
        float part = 0.f;
        if (slot < 127) {
            const unsigned short* hs = hl + (size_t)(i*127 + slot)*256 + half*128;
            const float* uu = u + half*128;
            #pragma unroll
            for (int d8 = 0; d8 < 16; ++d8) {
                bf16x8 v = *(const bf16x8*)(hs + d8*8);
                #pragma unroll
                for (int j = 0; j < 8; ++j)
                    part = fmaf(uu[d8*8 + j], b2f((unsigned short)v[j]), part);
            }
        }
        part += __shfl_xor(part, 1);
        if (slot < 127 && (half == 0)) lg[slot] = (part + c0s) * TEMPSC;
        if (tid == 255) lg[127] = -1e30f;
    }
    __syncthreads();
    if (tid < 64) {
        float a = fmaxf(lg[tid], lg[tid+64]);
        for (int off = 32; off; off >>= 1) a = fmaxf(a, __shfl_xor(a, off));
        if (tid == 0) smax = a;
    }
    __syncthreads();
    if (tid < 128) lg[tid] = (tid < 127) ? __expf(lg[tid] - smax) : 0.f;
    __syncthreads();
    if (tid < 64) {
        float a = lg[tid] + lg[tid+64];
        for (int off = 32; off; off >>= 1) a += __shfl_xor(a, off);
        if (tid == 0) ssum = a;
    }
    __syncthreads();
    {
        float acc = 0.f;
        for (int slot = 0; slot < 127; ++slot)
            acc = fmaf(lg[slot], b2f(hl[(size_t)(i*127 + slot)*256 + tid]), acc);
        cat[tid] = ht[tid];
        cat[256 + tid] = acc / ssum;
    }
    if (tid < 128) hnl[tid] = h_n[i*128 + tid];
    __syncthreads();
    if (tid < 64) {
        float p0 = nodes_t[i*2], p1 = nodes_t[i*2+1];
        xc[tid] = fmaxf(fmaf(n_enc_w[tid*2], p0, fmaf(n_enc_w[tid*2+1], p1, n_enc_b[tid])), 0.f);
    } else if (tid < 128) {
        int m = tid - 64;
        float s = n_attn_b[m];
        const float* wr = n_attn_w + m*512;
        for (int d = 0; d < 512; ++d) s = fmaf(wr[d], cat[d], s);
        xc[tid] = fmaxf(s, 0.f);
    }
    __syncthreads();
    #pragma unroll
    for (int rep = 0; rep < 2; ++rep) {
        int n = tid + rep*256;
        float s = n_bsum[n];
        for (int k = 0; k < 128; ++k) s = fmaf(n_wT[k*512 + n], xc[k], s);
        for (int k = 0; k < 128; ++k) s = fmaf(n_wT[(128+k)*512 + n], hnl[k], s);
        gl[n] = s;
    }
    __syncthreads();
    if (tid < 128) {
        float co = c_n[i*128 + tid];
        float c2 = sigm(gl[128+tid])*co + sigm(gl[tid])*tanhf(gl[256+tid]);
        float h2 = sigm(gl[384+tid])*tanhf(c2);
        c_n[i*128+tid] = c2;
        h_n[i*128+tid] = h2;
        hnl[tid] = h2;
    }
    __syncthreads();
    if (tid < 5) {
        float s = out_b[tid];
        const float* wr = out_w + tid*128;
        for (int k = 0; k < 128; ++k) s = fmaf(wr[k], hnl[k], s);
        out_t[i*5 + tid] = s;
    }
}

extern "C" void kernel_launch(void* const* d_in, const int* in_sizes, int n_in,
                              void* d_out, int out_size, void* d_ws, size_t ws_size,
                              hipStream_t stream)
{
    const float* nodes   = (const float*)d_in[0];
    const float* edges   = (const float*)d_in[1];
    const float* h_e0    = (const float*)d_in[2];
    const float* c_e0    = (const float*)d_in[3];
    const float* h_n0    = (const float*)d_in[4];
    const float* c_n0    = (const float*)d_in[5];
    const float* t_enc_w = (const float*)d_in[6];
    const float* t_enc_b = (const float*)d_in[7];
    const float* t_wih   = (const float*)d_in[8];
    const float* t_whh   = (const float*)d_in[9];
    const float* t_bih   = (const float*)d_in[10];
    const float* t_bhh   = (const float*)d_in[11];
    const float* s_enc_w = (const float*)d_in[12];
    const float* s_enc_b = (const float*)d_in[13];
    const float* s_wih   = (const float*)d_in[14];
    const float* s_whh   = (const float*)d_in[15];
    const float* s_bih   = (const float*)d_in[16];
    const float* s_bhh   = (const float*)d_in[17];
    const float* att_t_w = (const float*)d_in[18];
    const float* att_t_b = (const float*)d_in[19];
    const float* att_s_w = (const float*)d_in[20];
    const float* att_s_b = (const float*)d_in[21];
    const float* n_enc_w = (const float*)d_in[22];
    const float* n_enc_b = (const float*)d_in[23];
    const float* n_attn_w= (const float*)d_in[24];
    const float* n_attn_b= (const float*)d_in[25];
    const float* n_wih   = (const float*)d_in[26];
    const float* n_whh   = (const float*)d_in[27];
    const float* n_bih   = (const float*)d_in[28];
    const float* n_bhh   = (const float*)d_in[29];
    const float* out_w   = (const float*)d_in[30];
    const float* out_b   = (const float*)d_in[31];
    float* out = (float*)d_out;

    char* p = (char*)d_ws;
    float* c_all = (float*)p;            p += (size_t)16384*256*4;
    float* h_nn  = (float*)p;            p += 128*128*4;
    float* c_nn  = (float*)p;            p += 128*128*4;
    float* s_bs  = (float*)p;            p += 1024*4;
    float* t_bs  = (float*)p;            p += 1024*4;
    float* n_wT  = (float*)p;            p += 256*512*4;
    float* n_bs  = (float*)p;            p += 512*4;
    unsigned short* h_a  = (unsigned short*)p;  p += (size_t)16384*256*2;
    unsigned short* h_b  = (unsigned short*)p;  p += (size_t)16384*256*2;
    unsigned short* h_lin= (unsigned short*)p;  p += (size_t)16384*256*2;
    unsigned short* xenc = (unsigned short*)p;  p += (size_t)TT*16384*64*2;
    unsigned short* s_wHi = (unsigned short*)p; p += 1024*320*2;
    unsigned short* s_wLo = (unsigned short*)p; p += 1024*320*2;
    unsigned short* t_wHi = (unsigned short*)p; p += 1024*320*2;
    unsigned short* t_wLo = (unsigned short*)p; p += 1024*320*2;

    hipMemcpyAsync(h_nn, h_n0, 128*128*sizeof(float), hipMemcpyDeviceToDevice, stream);
    hipMemcpyAsync(c_nn, c_n0, 128*128*sizeof(float), hipMemcpyDeviceToDevice, stream);

    k_init_state<<<16384, 256, 0, stream>>>(h_e0, c_e0, h_a, c_all);
    k_prep_w<<<1280, 256, 0, stream>>>(s_wih, s_whh, s_wHi, s_wLo);
    k_prep_w<<<1280, 256, 0, stream>>>(t_wih, t_whh, t_wHi, t_wLo);
    k_prep_b<<<4, 256, 0, stream>>>(s_bih, s_bhh, s_bs);
    k_prep_b<<<4, 256, 0, stream>>>(t_bih, t_bhh, t_bs);
    k_prep_xenc<<<81920, 256, 0, stream>>>(edges, s_enc_w, s_enc_b, t_enc_w, t_enc_b, xenc);
    k_transpose<<<(512*128+255)/256, 256, 0, stream>>>(n_wih, n_wT, 512, 128);
    k_transpose<<<(512*128+255)/256, 256, 0, stream>>>(n_whh, n_wT + 128*512, 512, 128);
    k_bias_sum<<<2, 256, 0, stream>>>(n_bih, n_bhh, n_bs, 512);

    for (int t = 0; t < TT; ++t) {
        const unsigned short* h_in = (t & 1) ? h_b : h_a;
        unsigned short*       h_out= (t & 1) ? h_a : h_b;
        k_edge<<<2048, 256, 0, stream>>>(xenc + (size_t)t*16384*64,
            h_in, h_out, h_lin, c_all,
            s_wHi, s_wLo, s_bs, t_wHi, t_wLo, t_bs);
        k_node<<<NN, 256, 0, stream>>>(nodes + (size_t)t*NN*2, h_lin, h_nn, c_nn,
            out + (size_t)t*NN*5,
            att_t_w, att_t_b, att_s_w, att_s_b, n_enc_w, n_enc_b,
            n_attn_w, n_attn_b, n_wT, n_bs, out_w, out_b);
    }
}

// Round 11
// 1081.535 us; speedup vs baseline: 1.5436x; 1.3475x over previous
//
#include <hip/hip_runtime.h>
#include <cmath>

#define NN 128
#define TT 20
#define ERNN 256
#define TEMPSC 15.875f /* (N-1)/sqrt(ATT) = 127/8 */

typedef __attribute__((ext_vector_type(8))) short bf16x8;
typedef __attribute__((ext_vector_type(4))) float f32x4;

__device__ __forceinline__ float sigm(float x){ return 1.f/(1.f+__expf(-x)); }
__device__ __forceinline__ float b2f(unsigned short u){ union{unsigned int i; float f;} v; v.i = ((unsigned int)u)<<16; return v.f; }
__device__ __forceinline__ unsigned short f2b(float x){ union{float f; unsigned int u;} v; v.f = x; unsigned int r = v.u + 0x7fffu + ((v.u>>16)&1u); return (unsigned short)(r>>16); }

typedef __attribute__((address_space(3))) unsigned int lds_u32;
typedef __attribute__((address_space(1))) unsigned int glb_u32;
__device__ __forceinline__ void glds16(const void* g, void* l){
    __builtin_amdgcn_global_load_lds((const glb_u32*)g, (lds_u32*)l, 16, 0, 0);
}

// chunked h: [tile=r>>7][kc=d>>3 (32)][row=r&127][q=d&7]
__device__ __forceinline__ size_t hoff(int r, int d){
    return ((size_t)((r>>7)*32 + (d>>3))*128 + (r&127))*8 + (d&7);
}

__global__ void k_transpose(const float* __restrict__ s, float* __restrict__ d, int R, int C){
    int i = blockIdx.x*256 + threadIdx.x;
    if (i < R*C){ int r = i / C, c = i - r*C; d[c*R + r] = s[i]; }
}

__global__ void k_bias_sum(const float* __restrict__ a, const float* __restrict__ b,
                           float* __restrict__ o, int n){
    int i = blockIdx.x*256 + threadIdx.x;
    if (i < n) o[i] = a[i] + b[i];
}

// W chunked: [nt(8)][kchunk(40)][col(128)][8], col gate-interleaved (ch=(c>>6)*16+(c&15), g=(c>>4)&3)
__global__ void k_prep_w(const float* __restrict__ wih, const float* __restrict__ whh,
                         unsigned short* __restrict__ wHi, unsigned short* __restrict__ wLo){
    int idx = blockIdx.x*256 + threadIdx.x;
    if (idx >= 1024*320) return;
    int c = idx / 320, k = idx - c*320;
    int ch = ((c>>6)<<4) + (c&15), g = (c>>4)&3;
    int r = g*256 + ch;
    float v = (k < 64) ? wih[r*64 + k] : whh[r*256 + (k-64)];
    unsigned short hi = f2b(v);
    size_t dst = ((size_t)((c>>7)*40 + (k>>3))*128 + (c&127))*8 + (k&7);
    wHi[dst] = hi;
    wLo[dst] = f2b(v - b2f(hi));
}

__global__ void k_prep_b(const float* __restrict__ bih, const float* __restrict__ bhh,
                         float* __restrict__ bs){
    int c = blockIdx.x*256 + threadIdx.x;
    if (c < 1024){ int ch = ((c>>6)<<4)+(c&15), g=(c>>4)&3; int r = g*256+ch; bs[c] = bih[r] + bhh[r]; }
}

// encoder for ALL steps, write-coalesced: idx enumerates the chunked DEST
__global__ void k_prep_xenc(const float* __restrict__ edges,
                            const float* __restrict__ s_enc_w, const float* __restrict__ s_enc_b,
                            const float* __restrict__ t_enc_w, const float* __restrict__ t_enc_b,
                            unsigned short* __restrict__ xe){
    size_t idx = (size_t)blockIdx.x*256 + threadIdx.x;
    if (idx >= (size_t)TT*16384*64) return;
    int q = (int)(idx & 7);
    int row = (int)((idx >> 3) & 127);
    size_t rest = idx >> 10;
    int kc = (int)(rest & 7);
    int tile = (int)((rest >> 3) & 127);
    int t = (int)(rest >> 10);
    int r = tile*128 + row, m = kc*8 + q;
    bool sp = (r < 16256);
    int row_ij;
    if (sp) { int i = r/127, jj = r - i*127; row_ij = i*NN + jj + (jj>=i ? 1:0); }
    else    { row_ij = (r - 16256)*(NN+1); }
    const float* w = sp ? s_enc_w : t_enc_w;
    const float* b = sp ? s_enc_b : t_enc_b;
    float e0 = edges[((size_t)t*16384 + row_ij)*2];
    float e1 = edges[((size_t)t*16384 + row_ij)*2 + 1];
    xe[idx] = f2b(fmaxf(fmaf(w[m*2], e0, fmaf(w[m*2+1], e1, b[m])), 0.f));
}

// gather (i,j)-layout initial state into se-order; h chunked bf16, c linear fp32
__global__ void k_init_state(const float* __restrict__ h0, const float* __restrict__ c0,
                             unsigned short* __restrict__ hHi, float* __restrict__ c_all){
    int idx = blockIdx.x*256 + threadIdx.x;
    if (idx >= 16384*256) return;
    int r = idx >> 8, d = idx & 255;
    int row_ij;
    if (r < 16256){ int i = r/127, jj = r - i*127; row_ij = i*NN + jj + (jj>=i ? 1:0); }
    else          { row_ij = (r - 16256)*(NN+1); }
    hHi[hoff(r, d)] = f2b(h0[row_ij*ERNN + d]);
    c_all[idx] = c0[row_ij*ERNN + d];
}

// Edge LSTM: staged GEMM, X = [xenc(64) | h(256)], K=320, BK=32, 10 K-steps.
// BM=128 x BN=64, wave = 32 rows x 64 cols, acc[2][4]. LDS 16KB, grid 2048.
__global__ __launch_bounds__(256) void k_edge(
    const unsigned short* __restrict__ xenc_t,
    const unsigned short* __restrict__ h_in, unsigned short* __restrict__ h_out,
    unsigned short* __restrict__ hl_out, float* __restrict__ c_all,
    const unsigned short* __restrict__ s_wHi, const unsigned short* __restrict__ s_wLo,
    const float* __restrict__ s_bs,
    const unsigned short* __restrict__ t_wHi, const unsigned short* __restrict__ t_wLo,
    const float* __restrict__ t_bs)
{
    __shared__ unsigned short Ah[128*32];   // 8KB  [kc(4)][row(128)][8]
    __shared__ unsigned short Bh[64*32];    // 4KB  [kc(4)][col(64)][8]
    __shared__ unsigned short Bl[64*32];    // 4KB
    const int tid = threadIdx.x, lane = tid & 63, wid = tid >> 6;
    const int wg = (blockIdx.x & 7)*256 + (blockIdx.x >> 3);
    const int bm = wg >> 4, nt = wg & 15;
    const bool sp = (bm < 127);
    const int rbase = bm * 128;
    const unsigned short* wHi = sp ? s_wHi : t_wHi;
    const unsigned short* wLo = sp ? s_wLo : t_wLo;
    const float* bs = sp ? s_bs : t_bs;
    const int nt128 = nt >> 1, colh = (nt & 1)*64;

    auto stage = [&](int ks){
        const unsigned short* asrc = (ks < 2)
            ? xenc_t + ((size_t)bm*8  + ks*4     + wid)*1024
            : h_in   + ((size_t)bm*32 + (ks-2)*4 + wid)*1024;
        glds16(asrc + lane*8,       (char*)Ah + wid*2048);
        glds16(asrc + 512 + lane*8, (char*)Ah + wid*2048 + 1024);
        size_t wb = ((size_t)(nt128*40 + ks*4 + wid)*128 + colh)*8 + lane*8;
        glds16(wHi + wb, (char*)Bh + wid*1024);
        glds16(wLo + wb, (char*)Bl + wid*1024);
    };
    stage(0);

    f32x4 acc[2][4];
    #pragma unroll
    for (int m = 0; m < 2; ++m)
        #pragma unroll
        for (int g = 0; g < 4; ++g)
            acc[m][g] = (f32x4){0.f,0.f,0.f,0.f};

    const int arow = wid*32 + (lane & 15);
    const int bcol = lane & 15;
    const int kg = lane >> 4;
    for (int ks = 0; ; ++ks) {
        __syncthreads();
        bf16x8 a[2], bb[4];
        #pragma unroll
        for (int m = 0; m < 2; ++m) a[m] = *(const bf16x8*)&Ah[(kg*128 + arow + m*16)*8];
        #pragma unroll
        for (int g = 0; g < 4; ++g) bb[g] = *(const bf16x8*)&Bh[(kg*64 + bcol + g*16)*8];
        #pragma unroll
        for (int m = 0; m < 2; ++m)
            #pragma unroll
            for (int g = 0; g < 4; ++g)
                acc[m][g] = __builtin_amdgcn_mfma_f32_16x16x32_bf16(a[m], bb[g], acc[m][g], 0, 0, 0);
        #pragma unroll
        for (int g = 0; g < 4; ++g) bb[g] = *(const bf16x8*)&Bl[(kg*64 + bcol + g*16)*8];
        #pragma unroll
        for (int m = 0; m < 2; ++m)
            #pragma unroll
            for (int g = 0; g < 4; ++g)
                acc[m][g] = __builtin_amdgcn_mfma_f32_16x16x32_bf16(a[m], bb[g], acc[m][g], 0, 0, 0);
        if (ks == 9) break;
        __syncthreads();
        stage(ks+1);
    }

    const int chl = lane & 15, q4 = (lane >> 4)*4;
    const int ch = nt*16 + chl;
    const int cbase = nt*64 + chl;
    const float b0 = bs[cbase], b1 = bs[cbase+16], b2 = bs[cbase+32], b3 = bs[cbase+48];
    #pragma unroll
    for (int m = 0; m < 2; ++m) {
        #pragma unroll
        for (int rg = 0; rg < 4; ++rg) {
            int lrow = wid*32 + m*16 + q4 + rg;
            int row = rbase + lrow;
            float gi = acc[m][0][rg] + b0;
            float gf = acc[m][1][rg] + b1;
            float gg = acc[m][2][rg] + b2;
            float go = acc[m][3][rg] + b3;
            size_t off = (size_t)row*256 + ch;
            float c_old = c_all[off];
            float c2 = sigm(gf)*c_old + sigm(gi)*tanhf(gg);
            float h2 = sigm(go)*tanhf(c2);
            c_all[off] = c2;
            unsigned short hb = f2b(h2);
            h_out[((size_t)(bm*32 + (ch>>3))*128 + lrow)*8 + (ch&7)] = hb;
            hl_out[off] = hb;
        }
    }
}

// Per-node attention + node LSTM + output. 512 threads for TLP/MLP.
__global__ __launch_bounds__(512) void k_node(
    const float* __restrict__ nodes_t,
    const unsigned short* __restrict__ hl,       // [16384,256] bf16, se-order
    float* __restrict__ h_n, float* __restrict__ c_n,
    float* __restrict__ out_t,
    const float* __restrict__ att_t_w, const float* __restrict__ att_t_b,
    const float* __restrict__ att_s_w, const float* __restrict__ att_s_b,
    const float* __restrict__ n_enc_w, const float* __restrict__ n_enc_b,
    const float* __restrict__ n_attn_w, const float* __restrict__ n_attn_b,
    const float* __restrict__ n_wT, const float* __restrict__ n_bsum,
    const float* __restrict__ out_w, const float* __restrict__ out_b)
{
    const int i = blockIdx.x, tid = threadIdx.x;
    __shared__ float ht[ERNN];
    __shared__ float te[64];
    __shared__ float u[ERNN];
    __shared__ float lg[128];
    __shared__ float cat[512];
    __shared__ float xc[128];
    __shared__ float hnl[128];
    __shared__ float gl[512];
    __shared__ float pws[8][ERNN];
    __shared__ float smax, ssum, c0s;

    if (tid < 256) ht[tid] = b2f(hl[(size_t)(16256 + i)*256 + tid]);
    __syncthreads();
    // te: 4 threads per output row m (256 threads), 64 k each + 2-level shfl
    if (tid < 256) {
        int m = tid >> 2, q = tid & 3;
        float s = 0.f;
        const float* wr = att_t_w + m*ERNN + q*64;
        const float* hh = ht + q*64;
        #pragma unroll 8
        for (int k = 0; k < 64; ++k) s = fmaf(wr[k], hh[k], s);
        s += __shfl_xor(s, 1);
        s += __shfl_xor(s, 2);
        if (q == 0) te[m] = s + att_t_b[m];
    }
    __syncthreads();
    if (tid < 256) {              // u = att_s_w^T te
        float s = 0.f;
        for (int m = 0; m < 64; ++m) s = fmaf(att_s_w[m*ERNN + tid], te[m], s);
        u[tid] = s;
    }
    if (tid == 320) {
        float s = 0.f;
        for (int m = 0; m < 64; ++m) s = fmaf(te[m], att_s_b[m], s);
        c0s = s;
    }
    __syncthreads();
    // logits: 4 threads per slot (508 active), 8 independent 16B loads each
    {
        int slot = tid >> 2, q = tid & 3;
        float part = 0.f;
        if (slot < 127) {
            const unsigned short* hs = hl + (size_t)(i*127 + slot)*256 + q*64;
            const float* uu = u + q*64;
            #pragma unroll
            for (int d8 = 0; d8 < 8; ++d8) {
                bf16x8 v = *(const bf16x8*)(hs + d8*8);
                #pragma unroll
                for (int j = 0; j < 8; ++j)
                    part = fmaf(uu[d8*8 + j], b2f((unsigned short)v[j]), part);
            }
        }
        part += __shfl_xor(part, 1);
        part += __shfl_xor(part, 2);
        if (slot < 127 && q == 0) lg[slot] = (part + c0s) * TEMPSC;
        if (tid == 511) lg[127] = -1e30f;
    }
    __syncthreads();
    if (tid < 64) {
        float a = fmaxf(lg[tid], lg[tid+64]);
        for (int off = 32; off; off >>= 1) a = fmaxf(a, __shfl_xor(a, off));
        if (tid == 0) smax = a;
    }
    __syncthreads();
    if (tid < 128) lg[tid] = (tid < 127) ? __expf(lg[tid] - smax) : 0.f;
    __syncthreads();
    if (tid < 64) {
        float a = lg[tid] + lg[tid+64];
        for (int off = 32; off; off >>= 1) a += __shfl_xor(a, off);
        if (tid == 0) ssum = a;
    }
    __syncthreads();
    // weighted sum: wave w owns slots w*16..w*16+15; lane owns 4 channels (8B loads)
    {
        int w = tid >> 6, lane = tid & 63;
        float a0 = 0.f, a1 = 0.f, a2 = 0.f, a3 = 0.f;
        #pragma unroll 4
        for (int s = w*16; s < w*16 + 16; ++s) {
            int srow = (s < 127) ? s : 0;          // lg[127]==0 -> no contribution
            float wgt = lg[s];
            const unsigned short* hs = hl + (size_t)(i*127 + srow)*256 + lane*4;
            ushort4 v = *(const ushort4*)hs;
            a0 = fmaf(wgt, b2f(v.x), a0);
            a1 = fmaf(wgt, b2f(v.y), a1);
            a2 = fmaf(wgt, b2f(v.z), a2);
            a3 = fmaf(wgt, b2f(v.w), a3);
        }
        pws[w][lane*4+0] = a0; pws[w][lane*4+1] = a1;
        pws[w][lane*4+2] = a2; pws[w][lane*4+3] = a3;
    }
    if (tid >= 256 && tid < 384) hnl[tid-256] = h_n[i*128 + (tid-256)];
    __syncthreads();
    if (tid < 256) {
        float s = 0.f;
        #pragma unroll
        for (int w = 0; w < 8; ++w) s += pws[w][tid];
        cat[256 + tid] = s / ssum;
        cat[tid] = ht[tid];
    }
    __syncthreads();
    if (tid < 64) {               // enc
        float p0 = nodes_t[i*2], p1 = nodes_t[i*2+1];
        xc[tid] = fmaxf(fmaf(n_enc_w[tid*2], p0, fmaf(n_enc_w[tid*2+1], p1, n_enc_b[tid])), 0.f);
    }
    if (tid >= 256) {             // h_emb: 4 threads per output m (256 threads)
        int t2 = tid - 256;
        int m = t2 >> 2, q = t2 & 3;
        float s = 0.f;
        const float* wr = n_attn_w + m*512 + q*128;
        const float* cc = cat + q*128;
        #pragma unroll 8
        for (int d = 0; d < 128; ++d) s = fmaf(wr[d], cc[d], s);
        s += __shfl_xor(s, 1);
        s += __shfl_xor(s, 2);
        if (q == 0) xc[64 + m] = fmaxf(s + n_attn_b[m], 0.f);
    }
    __syncthreads();
    {                             // node LSTM gates: one thread per gate-channel
        int n = tid;
        float s = n_bsum[n];
        for (int k = 0; k < 128; ++k) s = fmaf(n_wT[k*512 + n], xc[k], s);
        for (int k = 0; k < 128; ++k) s = fmaf(n_wT[(128+k)*512 + n], hnl[k], s);
        gl[n] = s;
    }
    __syncthreads();
    if (tid < 128) {
        float co = c_n[i*128 + tid];
        float c2 = sigm(gl[128+tid])*co + sigm(gl[tid])*tanhf(gl[256+tid]);
        float h2 = sigm(gl[384+tid])*tanhf(c2);
        c_n[i*128+tid] = c2;
        h_n[i*128+tid] = h2;
        hnl[tid] = h2;
    }
    __syncthreads();
    if (tid < 5) {
        float s = out_b[tid];
        const float* wr = out_w + tid*128;
        for (int k = 0; k < 128; ++k) s = fmaf(wr[k], hnl[k], s);
        out_t[i*5 + tid] = s;
    }
}

extern "C" void kernel_launch(void* const* d_in, const int* in_sizes, int n_in,
                              void* d_out, int out_size, void* d_ws, size_t ws_size,
                              hipStream_t stream)
{
    const float* nodes   = (const float*)d_in[0];
    const float* edges   = (const float*)d_in[1];
    const float* h_e0    = (const float*)d_in[2];
    const float* c_e0    = (const float*)d_in[3];
    const float* h_n0    = (const float*)d_in[4];
    const float* c_n0    = (const float*)d_in[5];
    const float* t_enc_w = (const float*)d_in[6];
    const float* t_enc_b = (const float*)d_in[7];
    const float* t_wih   = (const float*)d_in[8];
    const float* t_whh   = (const float*)d_in[9];
    const float* t_bih   = (const float*)d_in[10];
    const float* t_bhh   = (const float*)d_in[11];
    const float* s_enc_w = (const float*)d_in[12];
    const float* s_enc_b = (const float*)d_in[13];
    const float* s_wih   = (const float*)d_in[14];
    const float* s_whh   = (const float*)d_in[15];
    const float* s_bih   = (const float*)d_in[16];
    const float* s_bhh   = (const float*)d_in[17];
    const float* att_t_w = (const float*)d_in[18];
    const float* att_t_b = (const float*)d_in[19];
    const float* att_s_w = (const float*)d_in[20];
    const float* att_s_b = (const float*)d_in[21];
    const float* n_enc_w = (const float*)d_in[22];
    const float* n_enc_b = (const float*)d_in[23];
    const float* n_attn_w= (const float*)d_in[24];
    const float* n_attn_b= (const float*)d_in[25];
    const float* n_wih   = (const float*)d_in[26];
    const float* n_whh   = (const float*)d_in[27];
    const float* n_bih   = (const float*)d_in[28];
    const float* n_bhh   = (const float*)d_in[29];
    const float* out_w   = (const float*)d_in[30];
    const float* out_b   = (const float*)d_in[31];
    float* out = (float*)d_out;

    char* p = (char*)d_ws;
    float* c_all = (float*)p;            p += (size_t)16384*256*4;
    float* h_nn  = (float*)p;            p += 128*128*4;
    float* c_nn  = (float*)p;            p += 128*128*4;
    float* s_bs  = (float*)p;            p += 1024*4;
    float* t_bs  = (float*)p;            p += 1024*4;
    float* n_wT  = (float*)p;            p += 256*512*4;
    float* n_bs  = (float*)p;            p += 512*4;
    unsigned short* h_a  = (unsigned short*)p;  p += (size_t)16384*256*2;
    unsigned short* h_b  = (unsigned short*)p;  p += (size_t)16384*256*2;
    unsigned short* h_lin= (unsigned short*)p;  p += (size_t)16384*256*2;
    unsigned short* xenc = (unsigned short*)p;  p += (size_t)TT*16384*64*2;
    unsigned short* s_wHi = (unsigned short*)p; p += 1024*320*2;
    unsigned short* s_wLo = (unsigned short*)p; p += 1024*320*2;
    unsigned short* t_wHi = (unsigned short*)p; p += 1024*320*2;
    unsigned short* t_wLo = (unsigned short*)p; p += 1024*320*2;

    hipMemcpyAsync(h_nn, h_n0, 128*128*sizeof(float), hipMemcpyDeviceToDevice, stream);
    hipMemcpyAsync(c_nn, c_n0, 128*128*sizeof(float), hipMemcpyDeviceToDevice, stream);

    k_init_state<<<16384, 256, 0, stream>>>(h_e0, c_e0, h_a, c_all);
    k_prep_w<<<1280, 256, 0, stream>>>(s_wih, s_whh, s_wHi, s_wLo);
    k_prep_w<<<1280, 256, 0, stream>>>(t_wih, t_whh, t_wHi, t_wLo);
    k_prep_b<<<4, 256, 0, stream>>>(s_bih, s_bhh, s_bs);
    k_prep_b<<<4, 256, 0, stream>>>(t_bih, t_bhh, t_bs);
    k_prep_xenc<<<81920, 256, 0, stream>>>(edges, s_enc_w, s_enc_b, t_enc_w, t_enc_b, xenc);
    k_transpose<<<(512*128+255)/256, 256, 0, stream>>>(n_wih, n_wT, 512, 128);
    k_transpose<<<(512*128+255)/256, 256, 0, stream>>>(n_whh, n_wT + 128*512, 512, 128);
    k_bias_sum<<<2, 256, 0, stream>>>(n_bih, n_bhh, n_bs, 512);

    for (int t = 0; t < TT; ++t) {
        const unsigned short* h_in = (t & 1) ? h_b : h_a;
        unsigned short*       h_out= (t & 1) ? h_a : h_b;
        k_edge<<<2048, 256, 0, stream>>>(xenc + (size_t)t*16384*64,
            h_in, h_out, h_lin, c_all,
            s_wHi, s_wLo, s_bs, t_wHi, t_wLo, t_bs);
        k_node<<<NN, 512, 0, stream>>>(nodes + (size_t)t*NN*2, h_lin, h_nn, c_nn,
            out + (size_t)t*NN*5,
            att_t_w, att_t_b, att_s_w, att_s_b, n_enc_w, n_enc_b,
            n_attn_w, n_attn_b, n_wT, n_bs, out_w, out_b);
    }
}

// Round 12
// 943.031 us; speedup vs baseline: 1.7703x; 1.1469x over previous
//
#include <hip/hip_runtime.h>
#include <cmath>

#define NN 128
#define TT 20
#define ERNN 256
#define TEMPSC 15.875f /* (N-1)/sqrt(ATT) = 127/8 */

typedef __attribute__((ext_vector_type(8))) short bf16x8;
typedef __attribute__((ext_vector_type(4))) float f32x4;

__device__ __forceinline__ float sigm(float x){ return 1.f/(1.f+__expf(-x)); }
__device__ __forceinline__ float b2f(unsigned short u){ union{unsigned int i; float f;} v; v.i = ((unsigned int)u)<<16; return v.f; }
__device__ __forceinline__ unsigned short f2b(float x){ union{float f; unsigned int u;} v; v.f = x; unsigned int r = v.u + 0x7fffu + ((v.u>>16)&1u); return (unsigned short)(r>>16); }

typedef __attribute__((address_space(3))) unsigned int lds_u32;
typedef __attribute__((address_space(1))) unsigned int glb_u32;
__device__ __forceinline__ void glds16(const void* g, void* l){
    __builtin_amdgcn_global_load_lds((const glb_u32*)g, (lds_u32*)l, 16, 0, 0);
}

// chunked h: [tile=r>>7][kc=d>>3 (32)][row=r&127][q=d&7]
__device__ __forceinline__ size_t hoff(int r, int d){
    return ((size_t)((r>>7)*32 + (d>>3))*128 + (r&127))*8 + (d&7);
}

__global__ void k_transpose(const float* __restrict__ s, float* __restrict__ d, int R, int C){
    int i = blockIdx.x*256 + threadIdx.x;
    if (i < R*C){ int r = i / C, c = i - r*C; d[c*R + r] = s[i]; }
}

__global__ void k_bias_sum(const float* __restrict__ a, const float* __restrict__ b,
                           float* __restrict__ o, int n){
    int i = blockIdx.x*256 + threadIdx.x;
    if (i < n) o[i] = a[i] + b[i];
}

// W chunked bf16: [nt(8)][kchunk(40)][col(128)][8], col gate-interleaved
__global__ void k_prep_w(const float* __restrict__ wih, const float* __restrict__ whh,
                         unsigned short* __restrict__ wHi){
    int idx = blockIdx.x*256 + threadIdx.x;
    if (idx >= 1024*320) return;
    int c = idx / 320, k = idx - c*320;
    int ch = ((c>>6)<<4) + (c&15), g = (c>>4)&3;
    int r = g*256 + ch;
    float v = (k < 64) ? wih[r*64 + k] : whh[r*256 + (k-64)];
    size_t dst = ((size_t)((c>>7)*40 + (k>>3))*128 + (c&127))*8 + (k&7);
    wHi[dst] = f2b(v);
}

__global__ void k_prep_b(const float* __restrict__ bih, const float* __restrict__ bhh,
                         float* __restrict__ bs){
    int c = blockIdx.x*256 + threadIdx.x;
    if (c < 1024){ int ch = ((c>>6)<<4)+(c&15), g=(c>>4)&3; int r = g*256+ch; bs[c] = bih[r] + bhh[r]; }
}

// encoder for ALL steps, chunked dest; thread computes 8 channels -> one 16B store
__global__ void k_prep_xenc(const float* __restrict__ edges,
                            const float* __restrict__ s_enc_w, const float* __restrict__ s_enc_b,
                            const float* __restrict__ t_enc_w, const float* __restrict__ t_enc_b,
                            unsigned short* __restrict__ xe){
    size_t g = (size_t)blockIdx.x*256 + threadIdx.x;   // 16B group index
    if (g >= (size_t)TT*16384*8) return;
    int row = (int)(g & 127);
    size_t rest = g >> 7;
    int kc = (int)(rest & 7);
    int tile = (int)((rest >> 3) & 127);
    int t = (int)(rest >> 10);
    int r = tile*128 + row;
    bool sp = (r < 16256);
    int row_ij;
    if (sp) { int i = r/127, jj = r - i*127; row_ij = i*NN + jj + (jj>=i ? 1:0); }
    else    { row_ij = (r - 16256)*(NN+1); }
    const float* w = sp ? s_enc_w : t_enc_w;
    const float* b = sp ? s_enc_b : t_enc_b;
    float e0 = edges[((size_t)t*16384 + row_ij)*2];
    float e1 = edges[((size_t)t*16384 + row_ij)*2 + 1];
    bf16x8 v8;
    #pragma unroll
    for (int q = 0; q < 8; ++q) {
        int m = kc*8 + q;
        v8[q] = (short)f2b(fmaxf(fmaf(w[m*2], e0, fmaf(w[m*2+1], e1, b[m])), 0.f));
    }
    *(bf16x8*)&xe[g*8] = v8;
}

// gather (i,j)-layout initial state into se-order; vectorized 8-wide
__global__ void k_init_state(const float* __restrict__ h0, const float* __restrict__ c0,
                             unsigned short* __restrict__ hHi, float* __restrict__ c_all){
    int g = blockIdx.x*256 + threadIdx.x;   // (r, d8) groups: 16384*32
    if (g >= 16384*32) return;
    int d8 = g & 31, r = g >> 5;
    int row_ij;
    if (r < 16256){ int i = r/127, jj = r - i*127; row_ij = i*NN + jj + (jj>=i ? 1:0); }
    else          { row_ij = (r - 16256)*(NN+1); }
    const float* hs = h0 + (size_t)row_ij*ERNN + d8*8;
    const float* cs = c0 + (size_t)row_ij*ERNN + d8*8;
    bf16x8 hb;
    #pragma unroll
    for (int q = 0; q < 8; ++q) hb[q] = (short)f2b(hs[q]);
    *(bf16x8*)&hHi[hoff(r, d8*8)] = hb;
    float* cd = c_all + (size_t)r*ERNN + d8*8;
    *(float4*)cd       = *(const float4*)cs;
    *(float4*)(cd + 4) = *(const float4*)(cs + 4);
}

// Edge LSTM: staged GEMM, X = [xenc(64) | h(256)], K=320, BK=32, 10 K-steps.
// 1-product bf16. BM=128 x BN=64, wave = 32 rows x 64 cols, acc[2][4]. LDS 12KB.
__global__ __launch_bounds__(256) void k_edge(
    const unsigned short* __restrict__ xenc_t,
    const unsigned short* __restrict__ h_in, unsigned short* __restrict__ h_out,
    unsigned short* __restrict__ hl_out, float* __restrict__ c_all,
    const unsigned short* __restrict__ s_wHi, const float* __restrict__ s_bs,
    const unsigned short* __restrict__ t_wHi, const float* __restrict__ t_bs)
{
    __shared__ unsigned short Ah[128*32];   // 8KB  [kc(4)][row(128)][8]
    __shared__ unsigned short Bh[64*32];    // 4KB  [kc(4)][col(64)][8]
    const int tid = threadIdx.x, lane = tid & 63, wid = tid >> 6;
    const int wg = (blockIdx.x & 7)*256 + (blockIdx.x >> 3);
    const int bm = wg >> 4, nt = wg & 15;
    const bool sp = (bm < 127);
    const int rbase = bm * 128;
    const unsigned short* wHi = sp ? s_wHi : t_wHi;
    const float* bs = sp ? s_bs : t_bs;
    const int nt128 = nt >> 1, colh = (nt & 1)*64;

    auto stage = [&](int ks){
        const unsigned short* asrc = (ks < 2)
            ? xenc_t + ((size_t)bm*8  + ks*4     + wid)*1024
            : h_in   + ((size_t)bm*32 + (ks-2)*4 + wid)*1024;
        glds16(asrc + lane*8,       (char*)Ah + wid*2048);
        glds16(asrc + 512 + lane*8, (char*)Ah + wid*2048 + 1024);
        size_t wb = ((size_t)(nt128*40 + ks*4 + wid)*128 + colh)*8 + lane*8;
        glds16(wHi + wb, (char*)Bh + wid*1024);
    };
    stage(0);

    f32x4 acc[2][4];
    #pragma unroll
    for (int m = 0; m < 2; ++m)
        #pragma unroll
        for (int g = 0; g < 4; ++g)
            acc[m][g] = (f32x4){0.f,0.f,0.f,0.f};

    const int arow = wid*32 + (lane & 15);
    const int bcol = lane & 15;
    const int kg = lane >> 4;
    for (int ks = 0; ; ++ks) {
        __syncthreads();
        bf16x8 a[2], bb[4];
        #pragma unroll
        for (int m = 0; m < 2; ++m) a[m] = *(const bf16x8*)&Ah[(kg*128 + arow + m*16)*8];
        #pragma unroll
        for (int g = 0; g < 4; ++g) bb[g] = *(const bf16x8*)&Bh[(kg*64 + bcol + g*16)*8];
        #pragma unroll
        for (int m = 0; m < 2; ++m)
            #pragma unroll
            for (int g = 0; g < 4; ++g)
                acc[m][g] = __builtin_amdgcn_mfma_f32_16x16x32_bf16(a[m], bb[g], acc[m][g], 0, 0, 0);
        if (ks == 9) break;
        __syncthreads();
        stage(ks+1);
    }

    const int chl = lane & 15, q4 = (lane >> 4)*4;
    const int ch = nt*16 + chl;
    const int cbase = nt*64 + chl;
    const float b0 = bs[cbase], b1 = bs[cbase+16], b2 = bs[cbase+32], b3 = bs[cbase+48];
    #pragma unroll
    for (int m = 0; m < 2; ++m) {
        #pragma unroll
        for (int rg = 0; rg < 4; ++rg) {
            int lrow = wid*32 + m*16 + q4 + rg;
            int row = rbase + lrow;
            float gi = acc[m][0][rg] + b0;
            float gf = acc[m][1][rg] + b1;
            float gg = acc[m][2][rg] + b2;
            float go = acc[m][3][rg] + b3;
            size_t off = (size_t)row*256 + ch;
            float c_old = c_all[off];
            float c2 = sigm(gf)*c_old + sigm(gi)*tanhf(gg);
            float h2 = sigm(go)*tanhf(c2);
            c_all[off] = c2;
            unsigned short hb = f2b(h2);
            h_out[((size_t)(bm*32 + (ch>>3))*128 + lrow)*8 + (ch&7)] = hb;
            hl_out[off] = hb;
        }
    }
}

// Per-node attention + node LSTM + output. 512 threads for TLP/MLP.
__global__ __launch_bounds__(512) void k_node(
    const float* __restrict__ nodes_t,
    const unsigned short* __restrict__ hl,       // [16384,256] bf16, se-order
    float* __restrict__ h_n, float* __restrict__ c_n,
    float* __restrict__ out_t,
    const float* __restrict__ att_t_w, const float* __restrict__ att_t_b,
    const float* __restrict__ att_s_w, const float* __restrict__ att_s_b,
    const float* __restrict__ n_enc_w, const float* __restrict__ n_enc_b,
    const float* __restrict__ n_attn_w, const float* __restrict__ n_attn_b,
    const float* __restrict__ n_wT, const float* __restrict__ n_bsum,
    const float* __restrict__ out_w, const float* __restrict__ out_b)
{
    const int i = blockIdx.x, tid = threadIdx.x;
    __shared__ float ht[ERNN];
    __shared__ float te[64];
    __shared__ float u[ERNN];
    __shared__ float lg[128];
    __shared__ float cat[512];
    __shared__ float xc[128];
    __shared__ float hnl[128];
    __shared__ float gl[512];
    __shared__ float pws[8][ERNN];
    __shared__ float smax, ssum, c0s;

    if (tid < 256) ht[tid] = b2f(hl[(size_t)(16256 + i)*256 + tid]);
    __syncthreads();
    if (tid < 256) {
        int m = tid >> 2, q = tid & 3;
        float s = 0.f;
        const float* wr = att_t_w + m*ERNN + q*64;
        const float* hh = ht + q*64;
        #pragma unroll 8
        for (int k = 0; k < 64; ++k) s = fmaf(wr[k], hh[k], s);
        s += __shfl_xor(s, 1);
        s += __shfl_xor(s, 2);
        if (q == 0) te[m] = s + att_t_b[m];
    }
    __syncthreads();
    if (tid < 256) {
        float s = 0.f;
        for (int m = 0; m < 64; ++m) s = fmaf(att_s_w[m*ERNN + tid], te[m], s);
        u[tid] = s;
    }
    if (tid == 320) {
        float s = 0.f;
        for (int m = 0; m < 64; ++m) s = fmaf(te[m], att_s_b[m], s);
        c0s = s;
    }
    __syncthreads();
    {
        int slot = tid >> 2, q = tid & 3;
        float part = 0.f;
        if (slot < 127) {
            const unsigned short* hs = hl + (size_t)(i*127 + slot)*256 + q*64;
            const float* uu = u + q*64;
            #pragma unroll
            for (int d8 = 0; d8 < 8; ++d8) {
                bf16x8 v = *(const bf16x8*)(hs + d8*8);
                #pragma unroll
                for (int j = 0; j < 8; ++j)
                    part = fmaf(uu[d8*8 + j], b2f((unsigned short)v[j]), part);
            }
        }
        part += __shfl_xor(part, 1);
        part += __shfl_xor(part, 2);
        if (slot < 127 && q == 0) lg[slot] = (part + c0s) * TEMPSC;
        if (tid == 511) lg[127] = -1e30f;
    }
    __syncthreads();
    if (tid < 64) {
        float a = fmaxf(lg[tid], lg[tid+64]);
        for (int off = 32; off; off >>= 1) a = fmaxf(a, __shfl_xor(a, off));
        if (tid == 0) smax = a;
    }
    __syncthreads();
    if (tid < 128) lg[tid] = (tid < 127) ? __expf(lg[tid] - smax) : 0.f;
    __syncthreads();
    if (tid < 64) {
        float a = lg[tid] + lg[tid+64];
        for (int off = 32; off; off >>= 1) a += __shfl_xor(a, off);
        if (tid == 0) ssum = a;
    }
    __syncthreads();
    {
        int w = tid >> 6, lane = tid & 63;
        float a0 = 0.f, a1 = 0.f, a2 = 0.f, a3 = 0.f;
        #pragma unroll 4
        for (int s = w*16; s < w*16 + 16; ++s) {
            int srow = (s < 127) ? s : 0;
            float wgt = lg[s];
            const unsigned short* hs = hl + (size_t)(i*127 + srow)*256 + lane*4;
            ushort4 v = *(const ushort4*)hs;
            a0 = fmaf(wgt, b2f(v.x), a0);
            a1 = fmaf(wgt, b2f(v.y), a1);
            a2 = fmaf(wgt, b2f(v.z), a2);
            a3 = fmaf(wgt, b2f(v.w), a3);
        }
        pws[w][lane*4+0] = a0; pws[w][lane*4+1] = a1;
        pws[w][lane*4+2] = a2; pws[w][lane*4+3] = a3;
    }
    if (tid >= 256 && tid < 384) hnl[tid-256] = h_n[i*128 + (tid-256)];
    __syncthreads();
    if (tid < 256) {
        float s = 0.f;
        #pragma unroll
        for (int w = 0; w < 8; ++w) s += pws[w][tid];
        cat[256 + tid] = s / ssum;
        cat[tid] = ht[tid];
    }
    __syncthreads();
    if (tid < 64) {
        float p0 = nodes_t[i*2], p1 = nodes_t[i*2+1];
        xc[tid] = fmaxf(fmaf(n_enc_w[tid*2], p0, fmaf(n_enc_w[tid*2+1], p1, n_enc_b[tid])), 0.f);
    }
    if (tid >= 256) {
        int t2 = tid - 256;
        int m = t2 >> 2, q = t2 & 3;
        float s = 0.f;
        const float* wr = n_attn_w + m*512 + q*128;
        const float* cc = cat + q*128;
        #pragma unroll 8
        for (int d = 0; d < 128; ++d) s = fmaf(wr[d], cc[d], s);
        s += __shfl_xor(s, 1);
        s += __shfl_xor(s, 2);
        if (q == 0) xc[64 + m] = fmaxf(s + n_attn_b[m], 0.f);
    }
    __syncthreads();
    {
        int n = tid;
        float s = n_bsum[n];
        for (int k = 0; k < 128; ++k) s = fmaf(n_wT[k*512 + n], xc[k], s);
        for (int k = 0; k < 128; ++k) s = fmaf(n_wT[(128+k)*512 + n], hnl[k], s);
        gl[n] = s;
    }
    __syncthreads();
    if (tid < 128) {
        float co = c_n[i*128 + tid];
        float c2 = sigm(gl[128+tid])*co + sigm(gl[tid])*tanhf(gl[256+tid]);
        float h2 = sigm(gl[384+tid])*tanhf(c2);
        c_n[i*128+tid] = c2;
        h_n[i*128+tid] = h2;
        hnl[tid] = h2;
    }
    __syncthreads();
    if (tid < 5) {
        float s = out_b[tid];
        const float* wr = out_w + tid*128;
        for (int k = 0; k < 128; ++k) s = fmaf(wr[k], hnl[k], s);
        out_t[i*5 + tid] = s;
    }
}

extern "C" void kernel_launch(void* const* d_in, const int* in_sizes, int n_in,
                              void* d_out, int out_size, void* d_ws, size_t ws_size,
                              hipStream_t stream)
{
    const float* nodes   = (const float*)d_in[0];
    const float* edges   = (const float*)d_in[1];
    const float* h_e0    = (const float*)d_in[2];
    const float* c_e0    = (const float*)d_in[3];
    const float* h_n0    = (const float*)d_in[4];
    const float* c_n0    = (const float*)d_in[5];
    const float* t_enc_w = (const float*)d_in[6];
    const float* t_enc_b = (const float*)d_in[7];
    const float* t_wih   = (const float*)d_in[8];
    const float* t_whh   = (const float*)d_in[9];
    const float* t_bih   = (const float*)d_in[10];
    const float* t_bhh   = (const float*)d_in[11];
    const float* s_enc_w = (const float*)d_in[12];
    const float* s_enc_b = (const float*)d_in[13];
    const float* s_wih   = (const float*)d_in[14];
    const float* s_whh   = (const float*)d_in[15];
    const float* s_bih   = (const float*)d_in[16];
    const float* s_bhh   = (const float*)d_in[17];
    const float* att_t_w = (const float*)d_in[18];
    const float* att_t_b = (const float*)d_in[19];
    const float* att_s_w = (const float*)d_in[20];
    const float* att_s_b = (const float*)d_in[21];
    const float* n_enc_w = (const float*)d_in[22];
    const float* n_enc_b = (const float*)d_in[23];
    const float* n_attn_w= (const float*)d_in[24];
    const float* n_attn_b= (const float*)d_in[25];
    const float* n_wih   = (const float*)d_in[26];
    const float* n_whh   = (const float*)d_in[27];
    const float* n_bih   = (const float*)d_in[28];
    const float* n_bhh   = (const float*)d_in[29];
    const float* out_w   = (const float*)d_in[30];
    const float* out_b   = (const float*)d_in[31];
    float* out = (float*)d_out;

    char* p = (char*)d_ws;
    float* c_all = (float*)p;            p += (size_t)16384*256*4;
    float* h_nn  = (float*)p;            p += 128*128*4;
    float* c_nn  = (float*)p;            p += 128*128*4;
    float* s_bs  = (float*)p;            p += 1024*4;
    float* t_bs  = (float*)p;            p += 1024*4;
    float* n_wT  = (float*)p;            p += 256*512*4;
    float* n_bs  = (float*)p;            p += 512*4;
    unsigned short* h_a  = (unsigned short*)p;  p += (size_t)16384*256*2;
    unsigned short* h_b  = (unsigned short*)p;  p += (size_t)16384*256*2;
    unsigned short* h_lin= (unsigned short*)p;  p += (size_t)16384*256*2;
    unsigned short* xenc = (unsigned short*)p;  p += (size_t)TT*16384*64*2;
    unsigned short* s_wHi = (unsigned short*)p; p += 1024*320*2;
    unsigned short* t_wHi = (unsigned short*)p; p += 1024*320*2;

    hipMemcpyAsync(h_nn, h_n0, 128*128*sizeof(float), hipMemcpyDeviceToDevice, stream);
    hipMemcpyAsync(c_nn, c_n0, 128*128*sizeof(float), hipMemcpyDeviceToDevice, stream);

    k_init_state<<<2048, 256, 0, stream>>>(h_e0, c_e0, h_a, c_all);
    k_prep_w<<<1280, 256, 0, stream>>>(s_wih, s_whh, s_wHi);
    k_prep_w<<<1280, 256, 0, stream>>>(t_wih, t_whh, t_wHi);
    k_prep_b<<<4, 256, 0, stream>>>(s_bih, s_bhh, s_bs);
    k_prep_b<<<4, 256, 0, stream>>>(t_bih, t_bhh, t_bs);
    k_prep_xenc<<<10240, 256, 0, stream>>>(edges, s_enc_w, s_enc_b, t_enc_w, t_enc_b, xenc);
    k_transpose<<<(512*128+255)/256, 256, 0, stream>>>(n_wih, n_wT, 512, 128);
    k_transpose<<<(512*128+255)/256, 256, 0, stream>>>(n_whh, n_wT + 128*512, 512, 128);
    k_bias_sum<<<2, 256, 0, stream>>>(n_bih, n_bhh, n_bs, 512);

    for (int t = 0; t < TT; ++t) {
        const unsigned short* h_in = (t & 1) ? h_b : h_a;
        unsigned short*       h_out= (t & 1) ? h_a : h_b;
        k_edge<<<2048, 256, 0, stream>>>(xenc + (size_t)t*16384*64,
            h_in, h_out, h_lin, c_all,
            s_wHi, s_bs, t_wHi, t_bs);
        k_node<<<NN, 512, 0, stream>>>(nodes + (size_t)t*NN*2, h_lin, h_nn, c_nn,
            out + (size_t)t*NN*5,
            att_t_w, att_t_b, att_s_w, att_s_b, n_enc_w, n_enc_b,
            n_attn_w, n_attn_b, n_wT, n_bs, out_w, out_b);
    }
}